// Round 1
// baseline (199.824 us; speedup 1.0000x reference)
//
#include <hip/hip_runtime.h>
#include <hip/hip_fp16.h>
#include <stdint.h>

// StyleHyperLinear on MI355X.
// out[b,t,o] = b_base[o] + sum_d x[b,t,d] * Weff[b,o,d]
// Weff[b] = w_base + mat_b[b] @ mat_a[b]   (LoRA folded; ALPHA=1)
// Hypernet (h, raw) computed exactly in fp32; main GEMM in fp16 MFMA w/ fp32 accum.

#define NB 8
#define NT 4096
#define DIN 512
#define DOUT 512
#define NSTYLE 256
#define RANK 8
#define NLORA ((DIN + DOUT) * RANK)  // 8192

typedef _Float16 f16x8 __attribute__((ext_vector_type(8)));
typedef float f32x4 __attribute__((ext_vector_type(4)));

// ---------------- kernel 1: h = silu(style @ w_h1^T + b_h1) ----------------
__global__ void k_hyper1(const float* __restrict__ style,
                         const float* __restrict__ w_h1,
                         const float* __restrict__ b_h1,
                         float* __restrict__ h) {
  const int b = blockIdx.x;
  const int j = threadIdx.x;  // 256 threads = NSTYLE outputs
  __shared__ float s[NSTYLE];
  s[j] = style[b * NSTYLE + j];
  __syncthreads();
  const float4* wrow = (const float4*)(w_h1 + (size_t)j * NSTYLE);
  float acc = b_h1[j];
#pragma unroll 8
  for (int k = 0; k < NSTYLE / 4; ++k) {
    float4 w4 = wrow[k];
    acc += s[4 * k + 0] * w4.x + s[4 * k + 1] * w4.y + s[4 * k + 2] * w4.z +
           s[4 * k + 3] * w4.w;
  }
  h[b * NSTYLE + j] = acc / (1.f + expf(-acc));  // silu
}

// ---------------- kernel 2: raw = h @ w_h2^T + b_h2 ----------------
__global__ void k_hyper2(const float* __restrict__ h,
                         const float* __restrict__ w_h2,
                         const float* __restrict__ b_h2,
                         float* __restrict__ raw) {
  const int b = blockIdx.y;
  const int n = blockIdx.x * 256 + threadIdx.x;
  __shared__ float hs[NSTYLE];
  hs[threadIdx.x] = h[b * NSTYLE + threadIdx.x];
  __syncthreads();
  const float4* wrow = (const float4*)(w_h2 + (size_t)n * NSTYLE);
  float acc = b_h2[n];
#pragma unroll 8
  for (int k = 0; k < NSTYLE / 4; ++k) {
    float4 w4 = wrow[k];
    acc += hs[4 * k + 0] * w4.x + hs[4 * k + 1] * w4.y + hs[4 * k + 2] * w4.z +
           hs[4 * k + 3] * w4.w;
  }
  raw[(size_t)b * NLORA + n] = acc;
}

// ---------------- kernel 3: Weff = w_base + B@A, cast -> fp16 ----------------
// raw[b, :4096]   = mat_a[b][r][d]  (r*512+d)
// raw[b, 4096: ]  = mat_b[b][o][r]  (o*8+r)
__global__ void k_weff(const float* __restrict__ raw,
                       const float* __restrict__ w_base,
                       _Float16* __restrict__ Wh) {
  const int oc = blockIdx.x;  // 32 chunks of 16 output rows
  const int b = blockIdx.y;
  __shared__ float Als[RANK][DIN];  // 16 KB
  __shared__ float Bls[16][RANK];
  const float* rb = raw + (size_t)b * NLORA;
  for (int i = threadIdx.x; i < RANK * DIN; i += 256)
    (&Als[0][0])[i] = rb[i];
  if (threadIdx.x < 16 * RANK) {
    int oo = threadIdx.x >> 3, r = threadIdx.x & 7;
    Bls[oo][r] = rb[DIN * RANK + (oc * 16 + oo) * RANK + r];
  }
  __syncthreads();
  for (int oo = 0; oo < 16; ++oo) {
    const int o = oc * 16 + oo;
    float br[RANK];
#pragma unroll
    for (int r = 0; r < RANK; ++r) br[r] = Bls[oo][r];
#pragma unroll
    for (int dd = 0; dd < DIN / 256; ++dd) {
      const int d = dd * 256 + threadIdx.x;
      float acc = w_base[(size_t)o * DIN + d];
#pragma unroll
      for (int r = 0; r < RANK; ++r) acc += br[r] * Als[r][d];
      Wh[((size_t)b * DOUT + o) * DIN + d] = (_Float16)acc;
    }
  }
}

// ---------------- kernel 4: main GEMM, fp16 MFMA ----------------
// out[b, mt*128 + i, nt*128 + j] over K=512. m97-style: 128x128 tile, BK=32,
// 4 waves, each wave a 64x64 subtile = 4x4 fragments of 16x16x32.
#define BM 128
#define BN 128
#define BK 32

__global__ __launch_bounds__(256) void k_gemm(const float* __restrict__ x,
                                              const _Float16* __restrict__ Wh,
                                              const float* __restrict__ b_base,
                                              float* __restrict__ out) {
  const int nt = blockIdx.x;  // 4
  const int mt = blockIdx.y;  // 32
  const int b = blockIdx.z;   // 8

  __shared__ _Float16 Xs[BM][BK];  // 8 KB, row-major [m][k]
  __shared__ _Float16 Ws[BN][BK];  // 8 KB, row-major [n][k]

  const int tid = threadIdx.x;
  const int lane = tid & 63;
  const int wave = tid >> 6;
  const int wr = wave >> 1, wc = wave & 1;  // 2x2 wave grid -> 64x64 each
  const int l16 = lane & 15, lq = lane >> 4;

  const float* xb = x + ((size_t)b * NT + (size_t)mt * BM) * DIN;
  const _Float16* wb = Wh + ((size_t)b * DOUT + (size_t)nt * BN) * DIN;

  f32x4 acc[4][4];
#pragma unroll
  for (int m = 0; m < 4; ++m)
#pragma unroll
    for (int n = 0; n < 4; ++n)
#pragma unroll
      for (int j = 0; j < 4; ++j) acc[m][n][j] = 0.f;

  // X staging map: thread -> (row i = tid>>1, k-offset (tid&1)*16), 16 floats.
  const int xi = tid >> 1;
  const int xk = (tid & 1) * 16;
  const float* xsrc = xb + (size_t)xi * DIN + xk;

  for (int k0 = 0; k0 < DIN; k0 += BK) {
    __syncthreads();  // previous iter's LDS readers done
    // --- stage X tile: global fp32 -> regs -> cvt fp16 -> LDS ---
    float4 f0 = *(const float4*)(xsrc + k0 + 0);
    float4 f1 = *(const float4*)(xsrc + k0 + 4);
    float4 f2 = *(const float4*)(xsrc + k0 + 8);
    float4 f3 = *(const float4*)(xsrc + k0 + 12);
    f16x8 h0, h1;
    h0[0] = (_Float16)f0.x; h0[1] = (_Float16)f0.y;
    h0[2] = (_Float16)f0.z; h0[3] = (_Float16)f0.w;
    h0[4] = (_Float16)f1.x; h0[5] = (_Float16)f1.y;
    h0[6] = (_Float16)f1.z; h0[7] = (_Float16)f1.w;
    h1[0] = (_Float16)f2.x; h1[1] = (_Float16)f2.y;
    h1[2] = (_Float16)f2.z; h1[3] = (_Float16)f2.w;
    h1[4] = (_Float16)f3.x; h1[5] = (_Float16)f3.y;
    h1[6] = (_Float16)f3.z; h1[7] = (_Float16)f3.w;
    *(f16x8*)&Xs[xi][xk] = h0;
    *(f16x8*)&Xs[xi][xk + 8] = h1;
    // --- stage W tile: async global->LDS, 16B/lane, linear layout ---
#pragma unroll
    for (int i = 0; i < 2; ++i) {
      const int c = i * 256 + wave * 64 + lane;  // 16B chunk id, 512 total
      const int jr = c >> 2;                     // row in tile
      const int kc = (c & 3) * 8;                // half-offset in row
      const _Float16* g = wb + (size_t)jr * DIN + k0 + kc;
      __builtin_amdgcn_global_load_lds(
          (const __attribute__((address_space(1))) void*)g,
          (__attribute__((address_space(3))) void*)((char*)&Ws[0][0] +
                                                    i * 4096 + wave * 1024),
          16, 0, 0);
    }
    __syncthreads();  // vmcnt+lgkm drained by compiler before barrier
    // --- fragments + MFMA ---
    f16x8 af[4], bf[4];
#pragma unroll
    for (int m = 0; m < 4; ++m)
      af[m] = *(const f16x8*)&Xs[wr * 64 + m * 16 + l16][lq * 8];
#pragma unroll
    for (int n = 0; n < 4; ++n)
      bf[n] = *(const f16x8*)&Ws[wc * 64 + n * 16 + l16][lq * 8];
#pragma unroll
    for (int m = 0; m < 4; ++m)
#pragma unroll
      for (int n = 0; n < 4; ++n)
        acc[m][n] = __builtin_amdgcn_mfma_f32_16x16x32_f16(af[m], bf[n],
                                                           acc[m][n], 0, 0, 0);
  }

  // --- epilogue: D mapping col=lane&15, row=(lane>>4)*4+reg ---
  float bv[4];
#pragma unroll
  for (int n = 0; n < 4; ++n)
    bv[n] = b_base[nt * BN + wc * 64 + n * 16 + l16];

#pragma unroll
  for (int m = 0; m < 4; ++m) {
#pragma unroll
    for (int j = 0; j < 4; ++j) {
      const int r = mt * BM + wr * 64 + m * 16 + lq * 4 + j;
      float* orow = out + ((size_t)b * NT + r) * DOUT + nt * BN;
#pragma unroll
      for (int n = 0; n < 4; ++n)
        orow[wc * 64 + n * 16 + l16] = acc[m][n][j] + bv[n];
    }
  }
}

// ---------------- launcher ----------------
extern "C" void kernel_launch(void* const* d_in, const int* in_sizes, int n_in,
                              void* d_out, int out_size, void* d_ws,
                              size_t ws_size, hipStream_t stream) {
  const float* x = (const float*)d_in[0];
  const float* style = (const float*)d_in[1];
  const float* w_base = (const float*)d_in[2];
  const float* b_base = (const float*)d_in[3];
  const float* w_h1 = (const float*)d_in[4];
  const float* b_h1 = (const float*)d_in[5];
  const float* w_h2 = (const float*)d_in[6];
  const float* b_h2 = (const float*)d_in[7];
  float* out = (float*)d_out;

  // workspace: h (8KB) | raw (256KB) | Wh fp16 (4MB)  -> ~4.3MB total
  char* ws = (char*)d_ws;
  float* h = (float*)ws;
  float* raw = (float*)(ws + 8192);
  _Float16* Wh = (_Float16*)(ws + 8192 + 262144);

  k_hyper1<<<NB, NSTYLE, 0, stream>>>(style, w_h1, b_h1, h);
  k_hyper2<<<dim3(NLORA / 256, NB), 256, 0, stream>>>(h, w_h2, b_h2, raw);
  k_weff<<<dim3(DOUT / 16, NB), 256, 0, stream>>>(raw, w_base, Wh);
  k_gemm<<<dim3(DOUT / BN, NT / BM, NB), 256, 0, stream>>>(x, Wh, b_base, out);
}

// Round 5
// 184.148 us; speedup vs baseline: 1.0851x; 1.0851x over previous
//
#include <hip/hip_runtime.h>
#include <hip/hip_fp16.h>
#include <stdint.h>

// StyleHyperLinear on MI355X.
// out[b,t,o] = b_base[o] + sum_d x[b,t,d] * Weff[b,o,d]
// Weff[b] = w_base + mat_b[b] @ mat_a[b]   (LoRA folded; ALPHA=1)
// Hypernet exact fp32; main GEMM fp16 MFMA w/ fp32 accum.
// v2 (resubmit x3): BN=512 (x fetched once), W pre-fragmented in L2 (no W
//     LDS), swizzled double-buffered Xs (1 barrier/K-step), coalesced hyper2.

#define NB 8
#define NT 4096
#define DIN 512
#define DOUT 512
#define NSTYLE 256
#define RANK 8
#define NLORA ((DIN + DOUT) * RANK)  // 8192

typedef _Float16 f16x8 __attribute__((ext_vector_type(8)));
typedef float f32x4 __attribute__((ext_vector_type(4)));

// ---------------- kernel 1: h = silu(style @ w_h1^T + b_h1) ----------------
__global__ void k_hyper1(const float* __restrict__ style,
                         const float* __restrict__ w_h1,
                         const float* __restrict__ b_h1,
                         float* __restrict__ h) {
  const int b = blockIdx.x;
  const int j = threadIdx.x;
  __shared__ float s[NSTYLE];
  s[j] = style[b * NSTYLE + j];
  __syncthreads();
  const float4* wrow = (const float4*)(w_h1 + (size_t)j * NSTYLE);
  float acc = b_h1[j];
#pragma unroll 8
  for (int k = 0; k < NSTYLE / 4; ++k) {
    float4 w4 = wrow[k];
    acc += s[4 * k + 0] * w4.x + s[4 * k + 1] * w4.y + s[4 * k + 2] * w4.z +
           s[4 * k + 3] * w4.w;
  }
  h[b * NSTYLE + j] = acc / (1.f + expf(-acc));
}

// ---------------- kernel 2: raw = h @ w_h2^T + b_h2 (coalesced) -----------
// One wave per w_h2 row n; 64 lanes read the 256-float row as float4 (1KB
// contiguous). All 8 batches computed per row via shuffle reduction.
__global__ __launch_bounds__(256) void k_hyper2(const float* __restrict__ h,
                                                const float* __restrict__ w_h2,
                                                const float* __restrict__ b_h2,
                                                float* __restrict__ raw) {
  __shared__ float hs[NB * NSTYLE];  // 8KB
  const int t = threadIdx.x;
#pragma unroll
  for (int i = 0; i < NB * NSTYLE / 256; ++i) hs[i * 256 + t] = h[i * 256 + t];
  __syncthreads();
  const int w = t >> 6, lane = t & 63;
  const int n = blockIdx.x * 4 + w;
  float4 w4 = *(const float4*)(w_h2 + (size_t)n * NSTYLE + lane * 4);
  float acc[NB];
#pragma unroll
  for (int b = 0; b < NB; ++b) {
    float4 hb = *(const float4*)(&hs[b * NSTYLE + lane * 4]);
    acc[b] = hb.x * w4.x + hb.y * w4.y + hb.z * w4.z + hb.w * w4.w;
#pragma unroll
    for (int m = 32; m > 0; m >>= 1) acc[b] += __shfl_xor(acc[b], m);
  }
  if (lane == 0) {
    const float bb = b_h2[n];
#pragma unroll
    for (int b = 0; b < NB; ++b) raw[(size_t)b * NLORA + n] = acc[b] + bb;
  }
}

// ---------------- kernel 3: Weff fragments -------------------------------
// Whf element layout (per batch b, region 512*512 fp16):
//   flat = cg*8192 + kkg*512 + lane*8 + j
//   holds Weff[b][o = cg*16 + (lane&15)][k = kkg*32 + (lane>>4)*8 + j]
// so the GEMM B-fragment read is a contiguous 1KB per-wave load.
__global__ void k_weff(const float* __restrict__ raw,
                       const float* __restrict__ w_base,
                       _Float16* __restrict__ Whf) {
  const int cg = blockIdx.x;  // 32 col-groups of 16 output rows
  const int b = blockIdx.y;
  const int t = threadIdx.x;
  __shared__ float Als[RANK * DIN];     // 16KB, mat_a flat r*512+d
  __shared__ float Wbs[16 * 516];       // 33KB, padded stride 516
  __shared__ float Bls[16][RANK];
  const float* rb = raw + (size_t)b * NLORA;
  // load mat_a (flat, coalesced float4)
#pragma unroll
  for (int i = 0; i < 4; ++i)
    *(float4*)(&Als[(i * 256 + t) * 4]) = *(const float4*)(&rb[(i * 256 + t) * 4]);
  // load w_base rows cg*16..+16 into padded LDS
#pragma unroll
  for (int i = 0; i < 8; ++i) {
    int fi = i * 256 + t;           // float4 id, 2048 total
    int oo = fi >> 7, d4 = fi & 127;
    float4 v = *(const float4*)(&w_base[((size_t)(cg * 16 + oo)) * DIN + d4 * 4]);
    *(float4*)(&Wbs[oo * 516 + d4 * 4]) = v;
  }
  if (t < 16 * RANK) {
    int oo = t >> 3, r = t & 7;
    Bls[oo][r] = rb[DIN * RANK + (cg * 16 + oo) * RANK + r];
  }
  __syncthreads();
  const int lane = t & 63;
  const int oo = lane & 15;
  const int koff = ((lane >> 4) & 3) * 8;
  float br[RANK];
#pragma unroll
  for (int r = 0; r < RANK; ++r) br[r] = Bls[oo][r];
  _Float16* dst = Whf + (size_t)b * (DOUT * DIN) + cg * 8192;
#pragma unroll
  for (int i = 0; i < 4; ++i) {
    const int q = i * 256 + t;       // [0,1024)
    const int kkg = q >> 6;          // [0,16)
    const int kb = kkg * 32 + koff;
    f16x8 v;
#pragma unroll
    for (int j = 0; j < 8; ++j) {
      float a = Wbs[oo * 516 + kb + j];
#pragma unroll
      for (int r = 0; r < RANK; ++r) a += br[r] * Als[r * DIN + kb + j];
      v[j] = (_Float16)a;
    }
    *(f16x8*)(dst + (size_t)q * 8) = v;
  }
}

// ---------------- kernel 4: main GEMM ------------------------------------
// BM=32, BN=512 (full DOUT), BK=64. 256 threads = 4 waves, wave w covers
// cols w*128 (8 col-groups). B-fragments straight from L2 (Whf layout).
// Xs double-buffered + XOR-swizzled; one barrier per K-step.
#define BM 32
#define BK 64

__global__ __launch_bounds__(256, 3) void k_gemm(
    const float* __restrict__ x, const _Float16* __restrict__ Whf,
    const float* __restrict__ b_base, float* __restrict__ out) {
  const int id = blockIdx.x;
  const int b = id & 7;       // same (id%8) -> same XCD: W_b stays L2-local
  const int mt = id >> 3;     // [0,128)
  const int t = threadIdx.x;
  const int lane = t & 63;
  const int w = t >> 6;
  const int l16 = lane & 15, lq = lane >> 4;

  __shared__ _Float16 Xs[2][BM * BK];  // 2 x 4KB, swizzled

  const float* xb = x + ((size_t)b * NT + (size_t)mt * BM) * DIN;
  const _Float16* wb = Whf + (size_t)b * (DOUT * DIN) + (size_t)(w * 8) * 8192 +
                       (size_t)lane * 8;

  f32x4 acc[2][8];
#pragma unroll
  for (int m = 0; m < 2; ++m)
#pragma unroll
    for (int n = 0; n < 8; ++n)
#pragma unroll
      for (int j = 0; j < 4; ++j) acc[m][n][j] = 0.f;

  // X staging map: thread t -> row=t>>3 (32 rows), chunk c=t&7 (8 x 16B)
  const int srow = t >> 3, sc = t & 7;
  const float* xsrc = xb + (size_t)srow * DIN + sc * 8;
  const int swz_w = (srow * 128 + sc * 16) ^ ((srow & 7) << 4);

  // prologue: stage step 0
  {
    float4 f0 = *(const float4*)(xsrc + 0);
    float4 f1 = *(const float4*)(xsrc + 4);
    f16x8 hh;
    hh[0] = (_Float16)f0.x; hh[1] = (_Float16)f0.y;
    hh[2] = (_Float16)f0.z; hh[3] = (_Float16)f0.w;
    hh[4] = (_Float16)f1.x; hh[5] = (_Float16)f1.y;
    hh[6] = (_Float16)f1.z; hh[7] = (_Float16)f1.w;
    *(f16x8*)((char*)&Xs[0][0] + swz_w) = hh;
  }
  __syncthreads();

  for (int step = 0; step < DIN / BK; ++step) {
    const int cur = step & 1;
    // prefetch next x tile into regs (overlaps with compute below)
    float4 f0p, f1p;
    if (step < DIN / BK - 1) {
      f0p = *(const float4*)(xsrc + (step + 1) * BK + 0);
      f1p = *(const float4*)(xsrc + (step + 1) * BK + 4);
    }
    // compute on Xs[cur]
#pragma unroll
    for (int kk = 0; kk < 2; ++kk) {
      const int kkg = step * 2 + kk;
      f16x8 af[2], bf[8];
#pragma unroll
      for (int m = 0; m < 2; ++m) {
        const int row = m * 16 + l16;
        const int byte = (row * 128 + (kk * 4 + lq) * 16) ^ ((row & 7) << 4);
        af[m] = *(const f16x8*)((const char*)&Xs[cur][0] + byte);
      }
#pragma unroll
      for (int n = 0; n < 8; ++n)
        bf[n] = *(const f16x8*)(wb + (size_t)n * 8192 + (size_t)kkg * 512);
#pragma unroll
      for (int m = 0; m < 2; ++m)
#pragma unroll
        for (int n = 0; n < 8; ++n)
          acc[m][n] = __builtin_amdgcn_mfma_f32_16x16x32_f16(af[m], bf[n],
                                                             acc[m][n], 0, 0, 0);
    }
    // write next tile into the other buffer
    if (step < DIN / BK - 1) {
      f16x8 hh;
      hh[0] = (_Float16)f0p.x; hh[1] = (_Float16)f0p.y;
      hh[2] = (_Float16)f0p.z; hh[3] = (_Float16)f0p.w;
      hh[4] = (_Float16)f1p.x; hh[5] = (_Float16)f1p.y;
      hh[6] = (_Float16)f1p.z; hh[7] = (_Float16)f1p.w;
      *(f16x8*)((char*)&Xs[cur ^ 1][0] + swz_w) = hh;
    }
    __syncthreads();
  }

  // epilogue: D mapping col=lane&15, row=(lane>>4)*4+reg
  float bv[8];
#pragma unroll
  for (int n = 0; n < 8; ++n) bv[n] = b_base[w * 128 + n * 16 + l16];

#pragma unroll
  for (int m = 0; m < 2; ++m) {
#pragma unroll
    for (int j = 0; j < 4; ++j) {
      const int r = mt * BM + m * 16 + lq * 4 + j;
      float* orow = out + ((size_t)b * NT + r) * DOUT;
#pragma unroll
      for (int n = 0; n < 8; ++n)
        orow[w * 128 + n * 16 + l16] = acc[m][n][j] + bv[n];
    }
  }
}

// ---------------- launcher ----------------
extern "C" void kernel_launch(void* const* d_in, const int* in_sizes, int n_in,
                              void* d_out, int out_size, void* d_ws,
                              size_t ws_size, hipStream_t stream) {
  const float* x = (const float*)d_in[0];
  const float* style = (const float*)d_in[1];
  const float* w_base = (const float*)d_in[2];
  const float* b_base = (const float*)d_in[3];
  const float* w_h1 = (const float*)d_in[4];
  const float* b_h1 = (const float*)d_in[5];
  const float* w_h2 = (const float*)d_in[6];
  const float* b_h2 = (const float*)d_in[7];
  float* out = (float*)d_out;

  // workspace: h (8KB) | raw (256KB) | Whf fp16 (4MB)
  char* ws = (char*)d_ws;
  float* h = (float*)ws;
  float* raw = (float*)(ws + 8192);
  _Float16* Whf = (_Float16*)(ws + 8192 + 262144);

  k_hyper1<<<NB, NSTYLE, 0, stream>>>(style, w_h1, b_h1, h);
  k_hyper2<<<NLORA / 4, 256, 0, stream>>>(h, w_h2, b_h2, raw);
  k_weff<<<dim3(DOUT / 16, NB), 256, 0, stream>>>(raw, w_base, Whf);
  k_gemm<<<(NT / BM) * NB, 256, 0, stream>>>(x, Whf, b_base, out);
}

// Round 6
// 181.233 us; speedup vs baseline: 1.1026x; 1.0161x over previous
//
#include <hip/hip_runtime.h>
#include <hip/hip_fp16.h>
#include <stdint.h>

// StyleHyperLinear on MI355X.
// out[b,t,o] = b_base[o] + sum_d x[b,t,d] * Weff[b,o,d]
// Weff[b] = w_base + mat_b[b] @ mat_a[b]   (LoRA folded; ALPHA=1)
// v3: k_gemm reworked to m97 structure — 128x128 tile, BK=64, W staged via
//     global_load_lds (async DMA, no VGPR cost; fixes v2's serialized L2
//     loads at VGPR=84), X reg-staged fp32->fp16 with XOR-swizzled LDS.
//     Whf remains fragment-major so linear gload_lds placement == the
//     ds_read_b128 fragment layout (64 lanes x 16B contiguous, 0-conflict).

#define NB 8
#define NT 4096
#define DIN 512
#define DOUT 512
#define NSTYLE 256
#define RANK 8
#define NLORA ((DIN + DOUT) * RANK)  // 8192

typedef _Float16 f16x8 __attribute__((ext_vector_type(8)));
typedef float f32x4 __attribute__((ext_vector_type(4)));

// ---------------- kernel 1: h = silu(style @ w_h1^T + b_h1) ----------------
__global__ void k_hyper1(const float* __restrict__ style,
                         const float* __restrict__ w_h1,
                         const float* __restrict__ b_h1,
                         float* __restrict__ h) {
  const int b = blockIdx.x;
  const int j = threadIdx.x;
  __shared__ float s[NSTYLE];
  s[j] = style[b * NSTYLE + j];
  __syncthreads();
  const float4* wrow = (const float4*)(w_h1 + (size_t)j * NSTYLE);
  float acc = b_h1[j];
#pragma unroll 8
  for (int k = 0; k < NSTYLE / 4; ++k) {
    float4 w4 = wrow[k];
    acc += s[4 * k + 0] * w4.x + s[4 * k + 1] * w4.y + s[4 * k + 2] * w4.z +
           s[4 * k + 3] * w4.w;
  }
  h[b * NSTYLE + j] = acc / (1.f + expf(-acc));
}

// ---------------- kernel 2: raw = h @ w_h2^T + b_h2 (coalesced) -----------
__global__ __launch_bounds__(256) void k_hyper2(const float* __restrict__ h,
                                                const float* __restrict__ w_h2,
                                                const float* __restrict__ b_h2,
                                                float* __restrict__ raw) {
  __shared__ float hs[NB * NSTYLE];  // 8KB
  const int t = threadIdx.x;
#pragma unroll
  for (int i = 0; i < NB * NSTYLE / 256; ++i) hs[i * 256 + t] = h[i * 256 + t];
  __syncthreads();
  const int w = t >> 6, lane = t & 63;
  const int n = blockIdx.x * 4 + w;
  float4 w4 = *(const float4*)(w_h2 + (size_t)n * NSTYLE + lane * 4);
  float acc[NB];
#pragma unroll
  for (int b = 0; b < NB; ++b) {
    float4 hb = *(const float4*)(&hs[b * NSTYLE + lane * 4]);
    acc[b] = hb.x * w4.x + hb.y * w4.y + hb.z * w4.z + hb.w * w4.w;
#pragma unroll
    for (int m = 32; m > 0; m >>= 1) acc[b] += __shfl_xor(acc[b], m);
  }
  if (lane == 0) {
    const float bb = b_h2[n];
#pragma unroll
    for (int b = 0; b < NB; ++b) raw[(size_t)b * NLORA + n] = acc[b] + bb;
  }
}

// ---------------- kernel 3: Weff fragments -------------------------------
// Whf element layout (per batch b, region 512*512 fp16):
//   flat = cg*8192 + kkg*512 + lane*8 + j
//   holds Weff[b][o = cg*16 + (lane&15)][k = kkg*32 + (lane>>4)*8 + j]
__global__ void k_weff(const float* __restrict__ raw,
                       const float* __restrict__ w_base,
                       _Float16* __restrict__ Whf) {
  const int cg = blockIdx.x;  // 32 col-groups of 16 output rows
  const int b = blockIdx.y;
  const int t = threadIdx.x;
  __shared__ float Als[RANK * DIN];     // 16KB, mat_a flat r*512+d
  __shared__ float Wbs[16 * 516];       // 33KB, padded stride 516
  __shared__ float Bls[16][RANK];
  const float* rb = raw + (size_t)b * NLORA;
#pragma unroll
  for (int i = 0; i < 4; ++i)
    *(float4*)(&Als[(i * 256 + t) * 4]) = *(const float4*)(&rb[(i * 256 + t) * 4]);
#pragma unroll
  for (int i = 0; i < 8; ++i) {
    int fi = i * 256 + t;           // float4 id, 2048 total
    int oo = fi >> 7, d4 = fi & 127;
    float4 v = *(const float4*)(&w_base[((size_t)(cg * 16 + oo)) * DIN + d4 * 4]);
    *(float4*)(&Wbs[oo * 516 + d4 * 4]) = v;
  }
  if (t < 16 * RANK) {
    int oo = t >> 3, r = t & 7;
    Bls[oo][r] = rb[DIN * RANK + (cg * 16 + oo) * RANK + r];
  }
  __syncthreads();
  const int lane = t & 63;
  const int oo = lane & 15;
  const int koff = ((lane >> 4) & 3) * 8;
  float br[RANK];
#pragma unroll
  for (int r = 0; r < RANK; ++r) br[r] = Bls[oo][r];
  _Float16* dst = Whf + (size_t)b * (DOUT * DIN) + cg * 8192;
#pragma unroll
  for (int i = 0; i < 4; ++i) {
    const int q = i * 256 + t;       // [0,1024)
    const int kkg = q >> 6;          // [0,16)
    const int kb = kkg * 32 + koff;
    f16x8 v;
#pragma unroll
    for (int j = 0; j < 8; ++j) {
      float a = Wbs[oo * 516 + kb + j];
#pragma unroll
      for (int r = 0; r < RANK; ++r) a += br[r] * Als[r * DIN + kb + j];
      v[j] = (_Float16)a;
    }
    *(f16x8*)(dst + (size_t)q * 8) = v;
  }
}

// ---------------- kernel 4: main GEMM (m97 structure) --------------------
// 128x128 tile, BK=64, 4 waves in 2x2 grid (64x64 subtile each, 4x4 frags).
// W: global_load_lds, fragment-linear (conflict-free b128 reads).
// X: reg-staged fp32->fp16, XOR-swizzled LDS (both sides).
#define BM 128
#define BN 128
#define BK 64

__global__ __launch_bounds__(256) void k_gemm(
    const float* __restrict__ x, const _Float16* __restrict__ Whf,
    const float* __restrict__ b_base, float* __restrict__ out) {
  const int id = blockIdx.x;
  const int b = id & 7;          // (id%8) -> XCD: W_b stays L2-local
  const int nt = (id >> 3) & 3;  // [0,4)
  const int mt = id >> 5;        // [0,32)
  const int t = threadIdx.x;
  const int lane = t & 63;
  const int wave = t >> 6;
  const int wr = wave >> 1, wc = wave & 1;
  const int l16 = lane & 15, lq = lane >> 4;

  __shared__ _Float16 Xs[BM * BK];  // 16KB, swizzled [row][k]
  __shared__ _Float16 Ws[BN * BK];  // 16KB, fragment-linear

  const float* xb = x + ((size_t)b * NT + (size_t)mt * BM) * DIN;
  const _Float16* wbt = Whf + (size_t)b * (DOUT * DIN) + (size_t)(nt * 8) * 8192;

  f32x4 acc[4][4];
#pragma unroll
  for (int m = 0; m < 4; ++m)
#pragma unroll
    for (int n = 0; n < 4; ++n)
#pragma unroll
      for (int j = 0; j < 4; ++j) acc[m][n][j] = 0.f;

  for (int step = 0; step < DIN / BK; ++step) {
    __syncthreads();  // prev step's LDS readers done
    // --- stage X: 4 pairs/thread, pair p -> row=p>>3, 8-float chunk o8=p&7
    //     (8 lanes cover one 256B row-slice contiguously -> coalesced) ---
#pragma unroll
    for (int i = 0; i < 4; ++i) {
      const int p = i * 256 + t;
      const int row = p >> 3, o8 = p & 7;
      const float* src = xb + (size_t)row * DIN + step * BK + o8 * 8;
      float4 f0 = *(const float4*)(src);
      float4 f1 = *(const float4*)(src + 4);
      f16x8 hh;
      hh[0] = (_Float16)f0.x; hh[1] = (_Float16)f0.y;
      hh[2] = (_Float16)f0.z; hh[3] = (_Float16)f0.w;
      hh[4] = (_Float16)f1.x; hh[5] = (_Float16)f1.y;
      hh[6] = (_Float16)f1.z; hh[7] = (_Float16)f1.w;
      const int byte = (row * 128 + o8 * 16) ^ ((row & 7) << 4);
      *(f16x8*)((char*)Xs + byte) = hh;
    }
    // --- stage W: async DMA, 4 x 16B/thread; LDS dest wave-uniform base ---
#pragma unroll
    for (int i = 0; i < 4; ++i) {
      const int c = i * 256 + t;  // chunk id [0,1024): 16KB tile
      const int cgr = c >> 7, kkr = (c >> 6) & 1, e = c & 63;
      const _Float16* g = wbt + (size_t)cgr * 8192 + (size_t)(step * 2 + kkr) * 512 + e * 8;
      __builtin_amdgcn_global_load_lds(
          (const __attribute__((address_space(1))) void*)g,
          (__attribute__((address_space(3))) void*)((char*)Ws +
                                                    (i * 256 + wave * 64) * 16),
          16, 0, 0);
    }
    __syncthreads();  // compiler drains vmcnt+lgkm before barrier
    // --- fragments + MFMA ---
#pragma unroll
    for (int kk = 0; kk < 2; ++kk) {
      f16x8 af[4], bf[4];
#pragma unroll
      for (int m = 0; m < 4; ++m) {
        const int row = wr * 64 + m * 16 + l16;
        const int byte = (row * 128 + (kk * 4 + lq) * 16) ^ ((row & 7) << 4);
        af[m] = *(const f16x8*)((const char*)Xs + byte);
      }
#pragma unroll
      for (int n = 0; n < 4; ++n)
        bf[n] = *(const f16x8*)((const char*)Ws +
                                (((wc * 4 + n) * 2 + kk) * 1024 + lane * 16));
#pragma unroll
      for (int m = 0; m < 4; ++m)
#pragma unroll
        for (int n = 0; n < 4; ++n)
          acc[m][n] = __builtin_amdgcn_mfma_f32_16x16x32_f16(af[m], bf[n],
                                                             acc[m][n], 0, 0, 0);
    }
  }

  // --- epilogue: D mapping col=lane&15, row=(lane>>4)*4+reg ---
  float bv[4];
#pragma unroll
  for (int n = 0; n < 4; ++n)
    bv[n] = b_base[nt * BN + wc * 64 + n * 16 + l16];

#pragma unroll
  for (int m = 0; m < 4; ++m) {
#pragma unroll
    for (int j = 0; j < 4; ++j) {
      const int r = mt * BM + wr * 64 + m * 16 + lq * 4 + j;
      float* orow = out + ((size_t)b * NT + r) * DOUT + nt * BN;
#pragma unroll
      for (int n = 0; n < 4; ++n)
        orow[wc * 64 + n * 16 + l16] = acc[m][n][j] + bv[n];
    }
  }
}

// ---------------- launcher ----------------
extern "C" void kernel_launch(void* const* d_in, const int* in_sizes, int n_in,
                              void* d_out, int out_size, void* d_ws,
                              size_t ws_size, hipStream_t stream) {
  const float* x = (const float*)d_in[0];
  const float* style = (const float*)d_in[1];
  const float* w_base = (const float*)d_in[2];
  const float* b_base = (const float*)d_in[3];
  const float* w_h1 = (const float*)d_in[4];
  const float* b_h1 = (const float*)d_in[5];
  const float* w_h2 = (const float*)d_in[6];
  const float* b_h2 = (const float*)d_in[7];
  float* out = (float*)d_out;

  // workspace: h (8KB) | raw (256KB) | Whf fp16 (4MB)
  char* ws = (char*)d_ws;
  float* h = (float*)ws;
  float* raw = (float*)(ws + 8192);
  _Float16* Whf = (_Float16*)(ws + 8192 + 262144);

  k_hyper1<<<NB, NSTYLE, 0, stream>>>(style, w_h1, b_h1, h);
  k_hyper2<<<NLORA / 4, 256, 0, stream>>>(h, w_h2, b_h2, raw);
  k_weff<<<dim3(DOUT / 16, NB), 256, 0, stream>>>(raw, w_base, Whf);
  k_gemm<<<(NT / BM) * (DOUT / BN) * NB, 256, 0, stream>>>(x, Whf, b_base, out);
}